// Round 9
// baseline (3630.456 us; speedup 1.0000x reference)
//
#include <hip/hip_runtime.h>
#include <stdint.h>

// Qwen3 decoder, 28L, Q=512, D=1024, HQ=16, HKV=8, HD=128, DFF=3072.
// R9: RMSNorm algebraically folded into GEMMs (ln weights folded into
// converted weight images; per-row scale applied post-GEMM; scale cancels
// for q/k under qk-norm). wo/wd split-K=1 with fused residual epilogue
// writing h + next A-image. 5 kernels/layer, no rms/finalize/parts.

typedef __bf16 bf16_t;
typedef _Float16 f16_t;
typedef __bf16 bf16x8 __attribute__((ext_vector_type(8)));
typedef __bf16 bf16x4 __attribute__((ext_vector_type(4)));
typedef _Float16 f16x8 __attribute__((ext_vector_type(8)));
typedef float f32x4 __attribute__((ext_vector_type(4)));

#define SEQ 512
#define HD 128

#define IMG_QKV 0ull
#define IMG_WO  8388608ull
#define IMG_GU  12582912ull
#define IMG_WD  25165824ull
#define IMG_LAYER_BYTES 31457280ull

typedef const __attribute__((address_space(1))) uint32_t as1_u32;
typedef __attribute__((address_space(3))) uint32_t as3_u32;

__device__ __forceinline__ void gload16(const void* g, void* l) {
    __builtin_amdgcn_global_load_lds((as1_u32*)g, (as3_u32*)l, 16, 0, 0);
}

#define WAITV12 asm volatile("s_waitcnt vmcnt(12)" ::: "memory")
#define WAITV6  asm volatile("s_waitcnt vmcnt(6)" ::: "memory")
#define WAITV0  asm volatile("s_waitcnt vmcnt(0)" ::: "memory")

__device__ __forceinline__ size_t aoff(int row, int col, int ldak) {
    return (((size_t)((row >> 6) * ldak + (col >> 6))) << 13) +
           ((size_t)(row & 63) << 7) +
           (size_t)((((col & 63) << 1)) ^ ((row & 7) << 4));
}

// ---------------------------------------------------------------------------
// copy h_in -> h (f32) and ximg (bf16 image) for layer 0
__global__ __launch_bounds__(256) void k_copy(const float* __restrict__ src,
                                              float* __restrict__ h,
                                              char* __restrict__ ximg)
{
    int t = blockIdx.x, tid = threadIdx.x;
    size_t base = (size_t)t * 1024 + tid * 4;
    float4 v = *(const float4*)(src + base);
    *(float4*)(h + base) = v;
    bf16x4 o;
    o[0] = (bf16_t)v.x; o[1] = (bf16_t)v.y; o[2] = (bf16_t)v.z; o[3] = (bf16_t)v.w;
    *(bf16x4*)(ximg + aoff(t, tid * 4, 16)) = o;
}

// ---------------------------------------------------------------------------
// weight tile convert (ln1 folded into Wq/Wk/Wv, ln2 into Wg/Wu)
__device__ __forceinline__ void conv_tile(
    int b, int lay,
    const float* __restrict__ Wq, const float* __restrict__ Wk,
    const float* __restrict__ Wv, const float* __restrict__ Wo,
    const float* __restrict__ Wg, const float* __restrict__ Wu,
    const float* __restrict__ Wd,
    const float* __restrict__ Ln1, const float* __restrict__ Ln2,
    char* __restrict__ ib, void* smemv)
{
    const float* wq = Wq + (size_t)lay * 1024 * 2048;
    const float* wk = Wk + (size_t)lay * 1024 * 1024;
    const float* wv = Wv + (size_t)lay * 1024 * 1024;
    const float* wo = Wo + (size_t)lay * 2048 * 1024;
    const float* wg = Wg + (size_t)lay * 1024 * 3072;
    const float* wu = Wu + (size_t)lay * 1024 * 3072;
    const float* wd = Wd + (size_t)lay * 3072 * 1024;

    const float* src = nullptr;
    const float* lnp = nullptr;
    int ldbw = 0, n, kt, guMode = 0;
    size_t dstoff;
    if (b < 1024) {                      // qkv: 64 n x 16 kt
        n = b >> 4; kt = b & 15;
        int C0 = n * 64;
        if (C0 < 2048)      { src = wq + C0;          ldbw = 2048; }
        else if (C0 < 3072) { src = wk + (C0 - 2048); ldbw = 1024; }
        else                { src = wv + (C0 - 3072); ldbw = 1024; }
        src += (size_t)(kt * 64) * ldbw;
        lnp = Ln1 + (size_t)lay * 1024 + kt * 64;
        dstoff = IMG_QKV + (size_t)b * 8192;
    } else if (b < 1536) {               // wo: 16 n x 32 kt
        int b2 = b - 1024; n = b2 >> 5; kt = b2 & 31;
        src = wo + (size_t)(kt * 64) * 1024 + n * 64; ldbw = 1024;
        dstoff = IMG_WO + (size_t)b2 * 8192;
    } else if (b < 3072) {               // gu: 96 n x 16 kt (g/u 16-interleave)
        int b3 = b - 1536; n = b3 >> 4; kt = b3 & 15;
        guMode = 1; ldbw = 3072;
        lnp = Ln2 + (size_t)lay * 1024 + kt * 64;
        dstoff = IMG_GU + (size_t)b3 * 8192;
    } else {                             // wd: 16 n x 48 kt
        int b4 = b - 3072; n = b4 / 48; kt = b4 % 48;
        src = wd + (size_t)(kt * 64) * 1024 + n * 64; ldbw = 1024;
        dstoff = IMG_WD + (size_t)b4 * 8192;
    }

    float (*T)[68] = (float (*)[68])smemv;
    int tid = threadIdx.x;
    if (!guMode) {
#pragma unroll
        for (int it = 0; it < 4; ++it) {
            int idx = it * 256 + tid;
            int kk = idx >> 4, seg = idx & 15;
            float4 vv = *(const float4*)(src + (size_t)kk * ldbw + seg * 4);
            if (lnp) {
                float s = lnp[kk];
                vv.x *= s; vv.y *= s; vv.z *= s; vv.w *= s;
            }
            *(float4*)&T[kk][seg * 4] = vv;
        }
    } else {
        const float* wg_ = wg + (size_t)(kt * 64) * 3072;
        const float* wu_ = wu + (size_t)(kt * 64) * 3072;
#pragma unroll
        for (int it = 0; it < 4; ++it) {
            int idx = it * 256 + tid;
            int kk = idx >> 4, seg = idx & 15;
            int nl = seg * 4;
            int colc = n * 32 + ((nl >> 5) & 1) * 16 + (nl & 15);
            const float* s2 = (((nl >> 4) & 1) ? wu_ : wg_) + (size_t)kk * 3072 + colc;
            float4 vv = *(const float4*)s2;
            float s = lnp[kk];
            vv.x *= s; vv.y *= s; vv.z *= s; vv.w *= s;
            *(float4*)&T[kk][nl] = vv;
        }
    }
    __syncthreads();
    char* dst = ib + dstoff;
#pragma unroll
    for (int it = 0; it < 2; ++it) {
        int kg = tid & 7;
        int nrow = it * 32 + (tid >> 3);
        bf16x8 o;
#pragma unroll
        for (int j = 0; j < 8; ++j) o[j] = (bf16_t)T[kg * 8 + j][nrow];
        *(bf16x8*)(dst + nrow * 128 + ((kg * 16) ^ ((nrow & 7) << 4))) = o;
    }
}

__global__ __launch_bounds__(256) void k_conv(
    int lay,
    const float* __restrict__ Wq, const float* __restrict__ Wk,
    const float* __restrict__ Wv, const float* __restrict__ Wo,
    const float* __restrict__ Wg, const float* __restrict__ Wu,
    const float* __restrict__ Wd,
    const float* __restrict__ Ln1, const float* __restrict__ Ln2,
    char* __restrict__ img)
{
    __shared__ __align__(16) char smem[17408];
    conv_tile(blockIdx.x, lay, Wq, Wk, Wv, Wo, Wg, Wu, Wd, Ln1, Ln2, img, smem);
}

// ---------------------------------------------------------------------------
// GEMM main loop: BM=64, BN=128, BK=64; 4 waves (2x2), 32x64 per wave.
template <int NBN, int SPLITK, int LDAK>
__device__ __forceinline__ void gemm_loop(
    const char* __restrict__ Aimg, const char* __restrict__ Bimg,
    char* smem, int f, f32x4 (&acc)[2][4], int& bmO, int& bnO)
{
    const int steps = LDAK / SPLITK;
    int bm = f / (NBN * SPLITK);
    int r = f % (NBN * SPLITK);
    int bn = r % NBN;
    bmO = bm; bnO = bn;

    int tid = threadIdx.x;
    int wv = tid >> 6, l = tid & 63, lg = l >> 4, lr = l & 15;
    int wr = wv >> 1, wc = wv & 1;

#pragma unroll
    for (int i = 0; i < 2; ++i)
#pragma unroll
        for (int j = 0; j < 4; ++j) { f32x4 z = {0.f, 0.f, 0.f, 0.f}; acc[i][j] = z; }

    auto stage = [&](int buf, int kt) {
        const char* ab = Aimg + ((size_t)(bm * LDAK + kt)) * 8192;
        const char* b0 = Bimg + ((size_t)((2 * bn) * LDAK + kt)) * 8192;
        const char* b1 = Bimg + ((size_t)((2 * bn + 1) * LDAK + kt)) * 8192;
        char* al = smem + buf * 24576;
        char* bl = al + 8192;
#pragma unroll
        for (int u = 0; u < 2; ++u) {
            int off = (wv * 2 + u) * 1024;
            gload16(ab + off + l * 16, al + off);
        }
#pragma unroll
        for (int u = 0; u < 4; ++u) {
            int off = (wv * 4 + u) * 1024;
            const char* src = (off < 8192) ? (b0 + off) : (b1 + off - 8192);
            gload16(src + l * 16, bl + off);
        }
    };
    auto compute = [&](int buf) {
        const char* as = smem + buf * 24576;
        const char* bs = as + 8192 + wc * 8192;
        __builtin_amdgcn_s_setprio(1);
#pragma unroll
        for (int c = 0; c < 2; ++c) {
            int co = (c * 64 + lg * 16) ^ ((lr & 7) << 4);
            bf16x8 af[2], bf[4];
#pragma unroll
            for (int i = 0; i < 2; ++i)
                af[i] = *(const bf16x8*)(as + (wr * 32 + i * 16 + lr) * 128 + co);
#pragma unroll
            for (int j = 0; j < 4; ++j)
                bf[j] = *(const bf16x8*)(bs + (j * 16 + lr) * 128 + co);
#pragma unroll
            for (int i = 0; i < 2; ++i)
#pragma unroll
                for (int j = 0; j < 4; ++j)
                    acc[i][j] = __builtin_amdgcn_mfma_f32_16x16x32_bf16(
                        af[i], bf[j], acc[i][j], 0, 0, 0);
        }
        __builtin_amdgcn_s_setprio(0);
    };

    stage(0, 0);
    stage(1, 1);
    int buf = 0;
    for (int kt = 0; kt < steps; ++kt) {
        if (kt + 2 < steps)      { stage((kt + 2) % 3, kt + 2); WAITV12; }
        else if (kt + 1 < steps) { WAITV6; }
        else                     { WAITV0; }
        __builtin_amdgcn_sched_barrier(0);
        __builtin_amdgcn_s_barrier();
        __builtin_amdgcn_sched_barrier(0);
        compute(buf);
        __builtin_amdgcn_s_barrier();
        buf = (buf == 2) ? 0 : buf + 1;
    }
}

// per-row rms scale: 4 threads per row sum 1024 f32 of h
__device__ __forceinline__ void row_scales(const float* __restrict__ h,
                                           int t0, float* sl)
{
    int tid = threadIdx.x;
    int r = tid >> 2, q4 = tid & 3;
    const float* hr = h + (size_t)(t0 + r) * 1024 + q4 * 256;
    float ss = 0.f;
#pragma unroll
    for (int c = 0; c < 64; ++c) {
        float4 v = *(const float4*)(hr + c * 4);
        ss += v.x * v.x + v.y * v.y + v.z * v.z + v.w * v.w;
    }
    ss += __shfl_xor(ss, 1);
    ss += __shfl_xor(ss, 2);
    if (q4 == 0) sl[r] = rsqrtf(ss * (1.0f / 1024.0f) + 1e-6f);
}

// ---------------------------------------------------------------------------
// qkv GEMM (A = bf16(h), B = ln1-folded W) + fused epilogues:
//   bn<24: per-head qk-RMSNorm + RoPE (row scale cancels under qk-norm)
//   bn>=24: V with row scale applied, transposed f16
__global__ __launch_bounds__(256) void g_qkvf(
    const char* __restrict__ Aimg, const char* __restrict__ Bimg,
    const float* __restrict__ cosb, const float* __restrict__ sinb,
    const float* __restrict__ qw, const float* __restrict__ kw,
    const float* __restrict__ h,
    f16_t* __restrict__ qf, f16_t* __restrict__ kf, f16_t* __restrict__ vT,
    const float* Wq, const float* Wk, const float* Wv, const float* Wo,
    const float* Wg, const float* Wu, const float* Wd,
    const float* Ln1, const float* Ln2,
    int lnext, char* __restrict__ imgnext)
{
    __shared__ __align__(128) char smem[73728];
    if (blockIdx.x >= 256) {
        conv_tile(blockIdx.x - 256, lnext, Wq, Wk, Wv, Wo, Wg, Wu, Wd,
                  Ln1, Ln2, imgnext, smem);
        return;
    }
    f32x4 acc[2][4];
    int bm, bn;
    gemm_loop<32, 1, 16>(Aimg, Bimg, smem, blockIdx.x, acc, bm, bn);

    int tid = threadIdx.x;
    int wv = tid >> 6, l = tid & 63, lg = l >> 4, lr = l & 15;
    int wr = wv >> 1, wc = wv & 1;
    float (*X)[132] = (float (*)[132])smem;
    float* sl = (float*)(smem + 64 * 132 * 4 + 128);
    __syncthreads();
#pragma unroll
    for (int i = 0; i < 2; ++i)
#pragma unroll
        for (int j = 0; j < 4; ++j)
#pragma unroll
            for (int ii = 0; ii < 4; ++ii)
                X[wr * 32 + i * 16 + lg * 4 + ii][wc * 64 + j * 16 + lr] = acc[i][j][ii];
    int t0 = bm * 64;
    if (bn >= 24) row_scales(h, t0, sl);
    __syncthreads();

    if (bn < 24) {
        bool isq = bn < 16;
        int slot = isq ? bn : bn - 16;
        const float* wn = isq ? qw : kw;
        int r = tid >> 2, part = tid & 3;
        float ss = 0.f;
#pragma unroll
        for (int c = 0; c < 32; ++c) { float v = X[r][part * 32 + c]; ss += v * v; }
        ss += __shfl_xor(ss, 1);
        ss += __shfl_xor(ss, 2);
        float sc = rsqrtf(ss * (1.0f / 128.0f) + 1e-6f);
        int t = t0 + r;
        int d0 = part * 16;
        float o1v[16], o2v[16];
#pragma unroll
        for (int c = 0; c < 16; ++c) {
            int d = d0 + c;
            float xv1 = X[r][d] * sc * wn[d];
            float xv2 = X[r][d + 64] * sc * wn[d + 64];
            o1v[c] = xv1 * cosb[t * HD + d] - xv2 * sinb[t * HD + d];
            o2v[c] = xv2 * cosb[t * HD + d + 64] + xv1 * sinb[t * HD + d + 64];
        }
        f16x8 w0, w1, w2, w3;
#pragma unroll
        for (int c = 0; c < 8; ++c) {
            w0[c] = (f16_t)o1v[c];     w1[c] = (f16_t)o1v[8 + c];
            w2[c] = (f16_t)o2v[c];     w3[c] = (f16_t)o2v[8 + c];
        }
        f16_t* o = (isq ? qf : kf) + ((size_t)slot * SEQ + t) * HD;
        *(f16x8*)(o + d0) = w0;
        *(f16x8*)(o + d0 + 8) = w1;
        *(f16x8*)(o + d0 + 64) = w2;
        *(f16x8*)(o + d0 + 72) = w3;
    } else {
        int kvh = bn - 24;
#pragma unroll
        for (int it = 0; it < 4; ++it) {
            int task = it * 256 + tid;
            int d = task >> 3, seg = task & 7;
            f16x8 o;
#pragma unroll
            for (int j = 0; j < 8; ++j)
                o[j] = (f16_t)(X[seg * 8 + j][d] * sl[seg * 8 + j]);
            *(f16x8*)(vT + ((size_t)kvh * HD + d) * SEQ + t0 + seg * 8) = o;
        }
    }
}

// ---------------------------------------------------------------------------
// wo GEMM (split-K=1, 64 blocks) + fused residual: h += out, write yimg
__global__ __launch_bounds__(256) void g_wo(
    const char* __restrict__ A, const char* __restrict__ B,
    float* __restrict__ h, char* __restrict__ yimg,
    const float* Wq, const float* Wk, const float* Wv, const float* Wo,
    const float* Wg, const float* Wu, const float* Wd,
    const float* Ln1, const float* Ln2,
    int lnext, char* imgnext)
{
    __shared__ __align__(128) char smem[73728];
    if (blockIdx.x >= 64) {
        conv_tile(blockIdx.x - 64 + 960, lnext, Wq, Wk, Wv, Wo, Wg, Wu, Wd,
                  Ln1, Ln2, imgnext, smem);
        return;
    }
    f32x4 acc[2][4];
    int bm, bn;
    gemm_loop<8, 1, 32>(A, B, smem, blockIdx.x, acc, bm, bn);
    int tid = threadIdx.x;
    int wv = tid >> 6, l = tid & 63, lg = l >> 4, lr = l & 15;
    int wr = wv >> 1, wc = wv & 1;
#pragma unroll
    for (int i = 0; i < 2; ++i)
#pragma unroll
        for (int j = 0; j < 4; ++j)
#pragma unroll
            for (int ii = 0; ii < 4; ++ii) {
                int row = bm * 64 + wr * 32 + i * 16 + lg * 4 + ii;
                int col = bn * 128 + wc * 64 + j * 16 + lr;
                float hv = h[(size_t)row * 1024 + col] + acc[i][j][ii];
                h[(size_t)row * 1024 + col] = hv;
                *(bf16_t*)(yimg + aoff(row, col, 16)) = (bf16_t)hv;
            }
}

// ---------------------------------------------------------------------------
// gu GEMM (B = ln2-folded, g/u paired) + row scale + swiglu -> mimg
__global__ __launch_bounds__(256) void g_gu(
    const char* __restrict__ A, const char* __restrict__ B,
    const float* __restrict__ h, char* __restrict__ mimg,
    const float* Wq, const float* Wk, const float* Wv, const float* Wo,
    const float* Wg, const float* Wu, const float* Wd,
    const float* Ln1, const float* Ln2,
    int lnext, char* imgnext)
{
    __shared__ __align__(128) char smem[73728];
    if (blockIdx.x >= 384) {
        conv_tile(blockIdx.x - 384 + 1920, lnext, Wq, Wk, Wv, Wo, Wg, Wu, Wd,
                  Ln1, Ln2, imgnext, smem);
        return;
    }
    f32x4 acc[2][4];
    int bm, bn;
    gemm_loop<48, 1, 16>(A, B, smem, blockIdx.x, acc, bm, bn);
    int tid = threadIdx.x;
    int wv = tid >> 6, l = tid & 63, lg = l >> 4, lr = l & 15;
    int wr = wv >> 1, wc = wv & 1;
    float* sarr = (float*)smem;
    row_scales(h, bm * 64, sarr);
    __syncthreads();
#pragma unroll
    for (int i = 0; i < 2; ++i)
#pragma unroll
        for (int jp = 0; jp < 2; ++jp)
#pragma unroll
            for (int ii = 0; ii < 4; ++ii) {
                int lrow = wr * 32 + i * 16 + lg * 4 + ii;
                int row = bm * 64 + lrow;
                int col = (bn * 2 + wc) * 32 + jp * 16 + lr;
                float s = sarr[lrow];
                float gv = acc[i][2 * jp][ii] * s;
                float uv = acc[i][2 * jp + 1][ii] * s;
                float val = gv / (1.f + __expf(-gv)) * uv;
                *(bf16_t*)(mimg + aoff(row, col, 48)) = (bf16_t)val;
            }
}

// ---------------------------------------------------------------------------
// wd GEMM (split-K=1, 64 blocks) + fused residual: h += out, write ximg
// (next layer A) or final f32 output.
__global__ __launch_bounds__(256) void g_wd(
    const char* __restrict__ A, const char* __restrict__ B,
    float* __restrict__ h, char* __restrict__ ximg, float* __restrict__ fout,
    const float* Wq, const float* Wk, const float* Wv, const float* Wo,
    const float* Wg, const float* Wu, const float* Wd,
    const float* Ln1, const float* Ln2,
    int lnext, char* imgnext)
{
    __shared__ __align__(128) char smem[73728];
    if (blockIdx.x >= 64) {
        conv_tile(blockIdx.x - 64 + 2880, lnext, Wq, Wk, Wv, Wo, Wg, Wu, Wd,
                  Ln1, Ln2, imgnext, smem);
        return;
    }
    f32x4 acc[2][4];
    int bm, bn;
    gemm_loop<8, 1, 48>(A, B, smem, blockIdx.x, acc, bm, bn);
    int tid = threadIdx.x;
    int wv = tid >> 6, l = tid & 63, lg = l >> 4, lr = l & 15;
    int wr = wv >> 1, wc = wv & 1;
#pragma unroll
    for (int i = 0; i < 2; ++i)
#pragma unroll
        for (int j = 0; j < 4; ++j)
#pragma unroll
            for (int ii = 0; ii < 4; ++ii) {
                int row = bm * 64 + wr * 32 + i * 16 + lg * 4 + ii;
                int col = bn * 128 + wc * 64 + j * 16 + lr;
                float hv = h[(size_t)row * 1024 + col] + acc[i][j][ii];
                if (fout) {
                    fout[(size_t)row * 1024 + col] = hv;
                } else {
                    h[(size_t)row * 1024 + col] = hv;
                    *(bf16_t*)(ximg + aoff(row, col, 16)) = (bf16_t)hv;
                }
            }
}

// ---------------------------------------------------------------------------
// causal flash attention -> attn-out image; heavy q-tiles launched first.
__global__ __launch_bounds__(128) void k_attn(
    const f16_t* __restrict__ qf, const f16_t* __restrict__ kf,
    const f16_t* __restrict__ vT, char* __restrict__ attimg)
{
    int h = blockIdx.x >> 4, qb = 15 - (blockIdx.x & 15);
    int kvh = h >> 1;
    __shared__ f16_t Kt[64][136];
    __shared__ f16_t Vt[128][72];
    __shared__ f16_t Pl[2][16][72];
    int tid = threadIdx.x;
    int wv = tid >> 6, l = tid & 63, lg = l >> 4, lr = l & 15;
    int q0 = qb * 32;
    int qrow = q0 + wv * 16;

    f16x8 aq[4];
    const f16_t* qp = qf + ((size_t)h * SEQ + qrow + lr) * HD;
#pragma unroll
    for (int c = 0; c < 4; ++c) aq[c] = *(const f16x8*)(qp + c * 32 + lg * 8);

    f32x4 accv[8];
#pragma unroll
    for (int df = 0; df < 8; ++df) { f32x4 z = {0.f, 0.f, 0.f, 0.f}; accv[df] = z; }
    float mrun[4], lrun[4];
#pragma unroll
    for (int ii = 0; ii < 4; ++ii) { mrun[ii] = -3e38f; lrun[ii] = 0.f; }

    int ktiles = (q0 + 32 + 63) >> 6;
    for (int kt = 0; kt < ktiles; ++kt) {
        int kt0 = kt * 64;
        __syncthreads();
#pragma unroll
        for (int it = 0; it < 8; ++it) {
            int idx = it * 128 + tid;
            int r = idx >> 4, seg = idx & 15;
            *(int4*)&Kt[r][seg * 8] =
                *(const int4*)(kf + ((size_t)kvh * SEQ + kt0 + r) * HD + seg * 8);
        }
#pragma unroll
        for (int it = 0; it < 8; ++it) {
            int idx = it * 128 + tid;
            int r = idx >> 3, seg = idx & 7;
            *(int4*)&Vt[r][seg * 8] =
                *(const int4*)(vT + ((size_t)kvh * HD + r) * SEQ + kt0 + seg * 8);
        }
        __syncthreads();

        f32x4 s[4];
#pragma unroll
        for (int nf = 0; nf < 4; ++nf) {
            f32x4 a = {0.f, 0.f, 0.f, 0.f};
#pragma unroll
            for (int c = 0; c < 4; ++c) {
                f16x8 bk = *(const f16x8*)&Kt[nf * 16 + lr][c * 32 + lg * 8];
                a = __builtin_amdgcn_mfma_f32_16x16x32_f16(aq[c], bk, a, 0, 0, 0);
            }
            s[nf] = a;
        }
        const float scale = 0.08838834764831845f;
        float tmax[4] = {-3e38f, -3e38f, -3e38f, -3e38f};
#pragma unroll
        for (int nf = 0; nf < 4; ++nf) {
            int ktg = kt0 + nf * 16 + lr;
#pragma unroll
            for (int ii = 0; ii < 4; ++ii) {
                int qg = qrow + lg * 4 + ii;
                float vv = s[nf][ii] * scale;
                vv = (ktg <= qg) ? vv : -1e30f;
                s[nf][ii] = vv;
                tmax[ii] = fmaxf(tmax[ii], vv);
            }
        }
#pragma unroll
        for (int m = 1; m < 16; m <<= 1)
#pragma unroll
            for (int ii = 0; ii < 4; ++ii)
                tmax[ii] = fmaxf(tmax[ii], __shfl_xor(tmax[ii], m));
        float corr[4];
#pragma unroll
        for (int ii = 0; ii < 4; ++ii) {
            float mnew = fmaxf(mrun[ii], tmax[ii]);
            corr[ii] = __expf(mrun[ii] - mnew);
            mrun[ii] = mnew;
        }
        float tsum[4] = {0.f, 0.f, 0.f, 0.f};
#pragma unroll
        for (int nf = 0; nf < 4; ++nf)
#pragma unroll
            for (int ii = 0; ii < 4; ++ii) {
                float pp = __expf(s[nf][ii] - mrun[ii]);
                s[nf][ii] = pp;
                tsum[ii] += pp;
            }
#pragma unroll
        for (int m = 1; m < 16; m <<= 1)
#pragma unroll
            for (int ii = 0; ii < 4; ++ii) tsum[ii] += __shfl_xor(tsum[ii], m);
#pragma unroll
        for (int ii = 0; ii < 4; ++ii) lrun[ii] = lrun[ii] * corr[ii] + tsum[ii];
#pragma unroll
        for (int df = 0; df < 8; ++df)
#pragma unroll
            for (int ii = 0; ii < 4; ++ii) accv[df][ii] *= corr[ii];
#pragma unroll
        for (int nf = 0; nf < 4; ++nf)
#pragma unroll
            for (int ii = 0; ii < 4; ++ii)
                Pl[wv][lg * 4 + ii][nf * 16 + lr] = (f16_t)s[nf][ii];
        __syncthreads();
#pragma unroll
        for (int c = 0; c < 2; ++c) {
            f16x8 ap = *(const f16x8*)&Pl[wv][lr][c * 32 + lg * 8];
#pragma unroll
            for (int df = 0; df < 8; ++df) {
                f16x8 bv = *(const f16x8*)&Vt[df * 16 + lr][c * 32 + lg * 8];
                accv[df] = __builtin_amdgcn_mfma_f32_16x16x32_f16(ap, bv, accv[df], 0, 0, 0);
            }
        }
    }
#pragma unroll
    for (int df = 0; df < 8; ++df)
#pragma unroll
        for (int ii = 0; ii < 4; ++ii) {
            int qg = qrow + lg * 4 + ii;
            int col = h * HD + df * 16 + lr;
            *(bf16_t*)(attimg + aoff(qg, col, 32)) =
                (bf16_t)(accv[df][ii] / lrun[ii]);
        }
}

// ---------------------------------------------------------------------------
extern "C" void kernel_launch(void* const* d_in, const int* in_sizes, int n_in,
                              void* d_out, int out_size, void* d_ws, size_t ws_size,
                              hipStream_t stream)
{
    const float* hin  = (const float*)d_in[0];
    const float* cosb = (const float*)d_in[1];
    const float* sinb = (const float*)d_in[2];
    const float* Wq = (const float*)d_in[4];
    const float* Wk = (const float*)d_in[5];
    const float* Wv = (const float*)d_in[6];
    const float* Wo = (const float*)d_in[7];
    const float* Wg = (const float*)d_in[8];
    const float* Wu = (const float*)d_in[9];
    const float* Wd = (const float*)d_in[10];
    const float* Ln1 = (const float*)d_in[11];
    const float* Ln2 = (const float*)d_in[12];
    const float* Qn = (const float*)d_in[13];
    const float* Kn = (const float*)d_in[14];

    char* p = (char*)d_ws;
    auto alloc = [&](size_t bytes) { char* r = p; p += bytes; return r; };
    float*  h     = (float*)alloc(2097152);
    char*   ximg  = alloc(1048576);
    char*   yimg  = alloc(1048576);
    char*   attimg= alloc(2097152);
    char*   mimg  = alloc(3145728);
    f16_t*  qf    = (f16_t*)alloc(2097152);
    f16_t*  kf    = (f16_t*)alloc(1048576);
    f16_t*  vT    = (f16_t*)alloc(1048576);
    char*   imgA  = alloc(IMG_LAYER_BYTES);
    size_t fixed = (size_t)(imgA + IMG_LAYER_BYTES - (char*)d_ws);
    bool pp = ws_size >= fixed + IMG_LAYER_BYTES;
    char* imgB = pp ? alloc(IMG_LAYER_BYTES) : imgA;

    k_copy<<<512, 256, 0, stream>>>(hin, h, ximg);
    if (pp)
        k_conv<<<3840, 256, 0, stream>>>(0, Wq, Wk, Wv, Wo, Wg, Wu, Wd,
                                         Ln1, Ln2, imgA);

    for (int l = 0; l < 28; ++l) {
        char* img  = pp ? ((l & 1) ? imgB : imgA) : imgA;
        char* imgn = pp ? ((l & 1) ? imgA : imgB) : imgA;
        bool cv = pp && (l < 27);
        int ln = l + 1;

        if (!pp)
            k_conv<<<3840, 256, 0, stream>>>(l, Wq, Wk, Wv, Wo, Wg, Wu, Wd,
                                             Ln1, Ln2, imgA);

        g_qkvf<<<cv ? 1216 : 256, 256, 0, stream>>>(
            ximg, img + IMG_QKV, cosb, sinb,
            Qn + (size_t)l * 128, Kn + (size_t)l * 128, h, qf, kf, vT,
            Wq, Wk, Wv, Wo, Wg, Wu, Wd, Ln1, Ln2, ln, imgn);
        k_attn<<<256, 128, 0, stream>>>(qf, kf, vT, attimg);
        g_wo<<<cv ? 1024 : 64, 256, 0, stream>>>(
            attimg, img + IMG_WO, h, yimg,
            Wq, Wk, Wv, Wo, Wg, Wu, Wd, Ln1, Ln2, ln, imgn);
        g_gu<<<cv ? 1344 : 384, 256, 0, stream>>>(
            yimg, img + IMG_GU, h, mimg,
            Wq, Wk, Wv, Wo, Wg, Wu, Wd, Ln1, Ln2, ln, imgn);
        g_wd<<<cv ? 1024 : 64, 256, 0, stream>>>(
            mimg, img + IMG_WD, h, ximg,
            (l == 27) ? (float*)d_out : nullptr,
            Wq, Wk, Wv, Wo, Wg, Wu, Wd, Ln1, Ln2, ln, imgn);
    }
}

// Round 10
// 3133.069 us; speedup vs baseline: 1.1588x; 1.1588x over previous
//
#include <hip/hip_runtime.h>
#include <stdint.h>

// Qwen3 decoder, 28L, Q=512, D=1024, HQ=16, HKV=8, HD=128, DFF=3072.
// R10: 5 kernels/layer. wo/wd split-K4 with f32 atomicAdd residual into h
// (no parts, no k_rms); qkv/gu reg-stage A from f32 h (ln folded in weights,
// row-scale in epilogue); conv distributed; attn heavy-first.

typedef __bf16 bf16_t;
typedef _Float16 f16_t;
typedef __bf16 bf16x8 __attribute__((ext_vector_type(8)));
typedef __bf16 bf16x4 __attribute__((ext_vector_type(4)));
typedef _Float16 f16x8 __attribute__((ext_vector_type(8)));
typedef float f32x4 __attribute__((ext_vector_type(4)));

#define SEQ 512
#define HD 128

#define IMG_QKV 0ull
#define IMG_WO  8388608ull
#define IMG_GU  12582912ull
#define IMG_WD  25165824ull
#define IMG_LAYER_BYTES 31457280ull

typedef const __attribute__((address_space(1))) uint32_t as1_u32;
typedef __attribute__((address_space(3))) uint32_t as3_u32;

__device__ __forceinline__ void gload16(const void* g, void* l) {
    __builtin_amdgcn_global_load_lds((as1_u32*)g, (as3_u32*)l, 16, 0, 0);
}

#define WAITV12 asm volatile("s_waitcnt vmcnt(12)" ::: "memory")
#define WAITV6  asm volatile("s_waitcnt vmcnt(6)" ::: "memory")
#define WAITV0  asm volatile("s_waitcnt vmcnt(0)" ::: "memory")

__device__ __forceinline__ size_t aoff(int row, int col, int ldak) {
    return (((size_t)((row >> 6) * ldak + (col >> 6))) << 13) +
           ((size_t)(row & 63) << 7) +
           (size_t)((((col & 63) << 1)) ^ ((row & 7) << 4));
}

// ---------------------------------------------------------------------------
__global__ __launch_bounds__(256) void k_copy(const float* __restrict__ src,
                                              float* __restrict__ dst)
{
    size_t i = ((size_t)blockIdx.x * 256 + threadIdx.x) * 4;
    *(float4*)(dst + i) = *(const float4*)(src + i);
}

// ---------------------------------------------------------------------------
// weight tile convert (ln1 folded into Wq/Wk/Wv, ln2 into Wg/Wu)
__device__ __forceinline__ void conv_tile(
    int b, int lay,
    const float* __restrict__ Wq, const float* __restrict__ Wk,
    const float* __restrict__ Wv, const float* __restrict__ Wo,
    const float* __restrict__ Wg, const float* __restrict__ Wu,
    const float* __restrict__ Wd,
    const float* __restrict__ Ln1, const float* __restrict__ Ln2,
    char* __restrict__ ib, void* smemv)
{
    const float* wq = Wq + (size_t)lay * 1024 * 2048;
    const float* wk = Wk + (size_t)lay * 1024 * 1024;
    const float* wv = Wv + (size_t)lay * 1024 * 1024;
    const float* wo = Wo + (size_t)lay * 2048 * 1024;
    const float* wg = Wg + (size_t)lay * 1024 * 3072;
    const float* wu = Wu + (size_t)lay * 1024 * 3072;
    const float* wd = Wd + (size_t)lay * 3072 * 1024;

    const float* src = nullptr;
    const float* lnp = nullptr;
    int ldbw = 0, n, kt, guMode = 0;
    size_t dstoff;
    if (b < 1024) {                      // qkv: 64 n x 16 kt
        n = b >> 4; kt = b & 15;
        int C0 = n * 64;
        if (C0 < 2048)      { src = wq + C0;          ldbw = 2048; }
        else if (C0 < 3072) { src = wk + (C0 - 2048); ldbw = 1024; }
        else                { src = wv + (C0 - 3072); ldbw = 1024; }
        src += (size_t)(kt * 64) * ldbw;
        lnp = Ln1 + (size_t)lay * 1024 + kt * 64;
        dstoff = IMG_QKV + (size_t)b * 8192;
    } else if (b < 1536) {               // wo: 16 n x 32 kt
        int b2 = b - 1024; n = b2 >> 5; kt = b2 & 31;
        src = wo + (size_t)(kt * 64) * 1024 + n * 64; ldbw = 1024;
        dstoff = IMG_WO + (size_t)b2 * 8192;
    } else if (b < 3072) {               // gu: 96 n x 16 kt (g/u 16-interleave)
        int b3 = b - 1536; n = b3 >> 4; kt = b3 & 15;
        guMode = 1; ldbw = 3072;
        lnp = Ln2 + (size_t)lay * 1024 + kt * 64;
        dstoff = IMG_GU + (size_t)b3 * 8192;
    } else {                             // wd: 16 n x 48 kt
        int b4 = b - 3072; n = b4 / 48; kt = b4 % 48;
        src = wd + (size_t)(kt * 64) * 1024 + n * 64; ldbw = 1024;
        dstoff = IMG_WD + (size_t)b4 * 8192;
    }

    float (*T)[68] = (float (*)[68])smemv;
    int tid = threadIdx.x;
    if (!guMode) {
#pragma unroll
        for (int it = 0; it < 4; ++it) {
            int idx = it * 256 + tid;
            int kk = idx >> 4, seg = idx & 15;
            float4 vv = *(const float4*)(src + (size_t)kk * ldbw + seg * 4);
            if (lnp) {
                float s = lnp[kk];
                vv.x *= s; vv.y *= s; vv.z *= s; vv.w *= s;
            }
            *(float4*)&T[kk][seg * 4] = vv;
        }
    } else {
        const float* wg_ = wg + (size_t)(kt * 64) * 3072;
        const float* wu_ = wu + (size_t)(kt * 64) * 3072;
#pragma unroll
        for (int it = 0; it < 4; ++it) {
            int idx = it * 256 + tid;
            int kk = idx >> 4, seg = idx & 15;
            int nl = seg * 4;
            int colc = n * 32 + ((nl >> 5) & 1) * 16 + (nl & 15);
            const float* s2 = (((nl >> 4) & 1) ? wu_ : wg_) + (size_t)kk * 3072 + colc;
            float4 vv = *(const float4*)s2;
            float s = lnp[kk];
            vv.x *= s; vv.y *= s; vv.z *= s; vv.w *= s;
            *(float4*)&T[kk][nl] = vv;
        }
    }
    __syncthreads();
    char* dst = ib + dstoff;
#pragma unroll
    for (int it = 0; it < 2; ++it) {
        int kg = tid & 7;
        int nrow = it * 32 + (tid >> 3);
        bf16x8 o;
#pragma unroll
        for (int j = 0; j < 8; ++j) o[j] = (bf16_t)T[kg * 8 + j][nrow];
        *(bf16x8*)(dst + nrow * 128 + ((kg * 16) ^ ((nrow & 7) << 4))) = o;
    }
}

__global__ __launch_bounds__(256) void k_conv(
    int lay,
    const float* __restrict__ Wq, const float* __restrict__ Wk,
    const float* __restrict__ Wv, const float* __restrict__ Wo,
    const float* __restrict__ Wg, const float* __restrict__ Wu,
    const float* __restrict__ Wd,
    const float* __restrict__ Ln1, const float* __restrict__ Ln2,
    char* __restrict__ img)
{
    __shared__ __align__(16) char smem[17408];
    conv_tile(blockIdx.x, lay, Wq, Wk, Wv, Wo, Wg, Wu, Wd, Ln1, Ln2, img, smem);
}

// ---------------------------------------------------------------------------
// shared MFMA compute for one 64x64 K-tile (as = A LDS base, bs adds wc half)
__device__ __forceinline__ void mfma_tile(const char* as, f32x4 (&acc)[2][4])
{
    int tid = threadIdx.x;
    int wv = tid >> 6, l = tid & 63, lg = l >> 4, lr = l & 15;
    int wr = wv >> 1, wc = wv & 1;
    const char* bs = as + 8192 + wc * 8192;
    __builtin_amdgcn_s_setprio(1);
#pragma unroll
    for (int c = 0; c < 2; ++c) {
        int co = (c * 64 + lg * 16) ^ ((lr & 7) << 4);
        bf16x8 af[2], bf[4];
#pragma unroll
        for (int i = 0; i < 2; ++i)
            af[i] = *(const bf16x8*)(as + (wr * 32 + i * 16 + lr) * 128 + co);
#pragma unroll
        for (int j = 0; j < 4; ++j)
            bf[j] = *(const bf16x8*)(bs + (j * 16 + lr) * 128 + co);
#pragma unroll
        for (int i = 0; i < 2; ++i)
#pragma unroll
            for (int j = 0; j < 4; ++j)
                acc[i][j] = __builtin_amdgcn_mfma_f32_16x16x32_bf16(
                    af[i], bf[j], acc[i][j], 0, 0, 0);
    }
    __builtin_amdgcn_s_setprio(0);
}

// ---------------------------------------------------------------------------
// image-A GEMM loop (wo/wd): 3-deep gload_lds pipeline, split-K.
template <int NBN, int SPLITK, int LDAK>
__device__ __forceinline__ void gemm_img(
    const char* __restrict__ Aimg, const char* __restrict__ Bimg,
    char* smem, int f, f32x4 (&acc)[2][4], int& bmO, int& bnO)
{
    const int steps = LDAK / SPLITK;
    int bm = f / (NBN * SPLITK);
    int r = f % (NBN * SPLITK);
    int s = r / NBN;
    int bn = r % NBN;
    int k0d = s * steps;
    bmO = bm; bnO = bn;

    int tid = threadIdx.x;
    int wv = tid >> 6, l = tid & 63;

#pragma unroll
    for (int i = 0; i < 2; ++i)
#pragma unroll
        for (int j = 0; j < 4; ++j) { f32x4 z = {0.f, 0.f, 0.f, 0.f}; acc[i][j] = z; }

    auto stage = [&](int buf, int kt) {
        const char* ab = Aimg + ((size_t)(bm * LDAK + k0d + kt)) * 8192;
        const char* b0 = Bimg + ((size_t)((2 * bn) * LDAK + k0d + kt)) * 8192;
        const char* b1 = Bimg + ((size_t)((2 * bn + 1) * LDAK + k0d + kt)) * 8192;
        char* al = smem + buf * 24576;
        char* bl = al + 8192;
#pragma unroll
        for (int u = 0; u < 2; ++u) {
            int off = (wv * 2 + u) * 1024;
            gload16(ab + off + l * 16, al + off);
        }
#pragma unroll
        for (int u = 0; u < 4; ++u) {
            int off = (wv * 4 + u) * 1024;
            const char* src = (off < 8192) ? (b0 + off) : (b1 + off - 8192);
            gload16(src + l * 16, bl + off);
        }
    };

    stage(0, 0);
    stage(1, 1);
    int buf = 0;
    for (int kt = 0; kt < steps; ++kt) {
        if (kt + 2 < steps)      { stage((kt + 2) % 3, kt + 2); WAITV12; }
        else if (kt + 1 < steps) { WAITV6; }
        else                     { WAITV0; }
        __builtin_amdgcn_sched_barrier(0);
        __builtin_amdgcn_s_barrier();
        __builtin_amdgcn_sched_barrier(0);
        mfma_tile(smem + buf * 24576, acc);
        __builtin_amdgcn_s_barrier();
        buf = (buf == 2) ? 0 : buf + 1;
    }
}

// ---------------------------------------------------------------------------
// reg-staged-A GEMM loop (qkv/gu): A loaded f32 from h, cvt->LDS; B gload_lds.
// K=1024 (16 steps), double-buffered, drain barriers (loop not bottleneck).
template <int NBN>
__device__ __forceinline__ void gemm_regA(
    const float* __restrict__ Ah, const char* __restrict__ Bimg,
    char* smem, int f, f32x4 (&acc)[2][4], int& bmO, int& bnO)
{
    const int steps = 16;
    int bm = f / NBN;
    int bn = f % NBN;
    bmO = bm; bnO = bn;

    int tid = threadIdx.x;
    int wv = tid >> 6, l = tid & 63;
    int ar = tid >> 2, ac4 = tid & 3;
    const float* Ap = Ah + (size_t)(bm * 64 + ar) * 1024 + ac4 * 16;

#pragma unroll
    for (int i = 0; i < 2; ++i)
#pragma unroll
        for (int j = 0; j < 4; ++j) { f32x4 z = {0.f, 0.f, 0.f, 0.f}; acc[i][j] = z; }

    float4 aR[4];
    auto loadA = [&](int kt) {
        const float* p = Ap + kt * 64;
#pragma unroll
        for (int q = 0; q < 4; ++q) aR[q] = *(const float4*)(p + q * 4);
    };
    auto writeA = [&](int buf) {
        char* al = smem + buf * 24576;
        const float* fa = (const float*)aR;
#pragma unroll
        for (int seg = 0; seg < 2; ++seg) {
            bf16x8 o;
#pragma unroll
            for (int j = 0; j < 8; ++j) o[j] = (bf16_t)fa[seg * 8 + j];
            *(bf16x8*)(al + ar * 128 + ((ac4 * 32 + seg * 16) ^ ((ar & 7) << 4))) = o;
        }
    };
    auto issueB = [&](int buf, int kt) {
        const char* b0 = Bimg + ((size_t)((2 * bn) * 16 + kt)) * 8192;
        const char* b1 = Bimg + ((size_t)((2 * bn + 1) * 16 + kt)) * 8192;
        char* bl = smem + buf * 24576 + 8192;
#pragma unroll
        for (int u = 0; u < 4; ++u) {
            int off = (wv * 4 + u) * 1024;
            const char* src = (off < 8192) ? (b0 + off) : (b1 + off - 8192);
            gload16(src + l * 16, bl + off);
        }
    };

    loadA(0); issueB(0, 0); writeA(0);
    __syncthreads();
    int buf = 0;
    for (int kt = 0; kt < steps; ++kt) {
        if (kt + 1 < steps) { loadA(kt + 1); issueB(buf ^ 1, kt + 1); }
        mfma_tile(smem + buf * 24576, acc);
        if (kt + 1 < steps) writeA(buf ^ 1);
        __syncthreads();
        buf ^= 1;
    }
}

// per-row rms scale from f32 h: 4 threads per row
__device__ __forceinline__ void row_scales(const float* __restrict__ h,
                                           int t0, float* sl)
{
    int tid = threadIdx.x;
    int r = tid >> 2, q4 = tid & 3;
    const float* hr = h + (size_t)(t0 + r) * 1024 + q4 * 256;
    float ss = 0.f;
#pragma unroll
    for (int c = 0; c < 64; ++c) {
        float4 v = *(const float4*)(hr + c * 4);
        ss += v.x * v.x + v.y * v.y + v.z * v.z + v.w * v.w;
    }
    ss += __shfl_xor(ss, 1);
    ss += __shfl_xor(ss, 2);
    if (q4 == 0) sl[r] = rsqrtf(ss * (1.0f / 1024.0f) + 1e-6f);
}

// ---------------------------------------------------------------------------
// qkv GEMM (reg-A from h, ln1-folded B) + qk-norm/rope + V(+s) epilogues.
__global__ __launch_bounds__(256) void g_qkv(
    const float* __restrict__ h, const char* __restrict__ Bimg,
    const float* __restrict__ cosb, const float* __restrict__ sinb,
    const float* __restrict__ qw, const float* __restrict__ kw,
    f16_t* __restrict__ qf, f16_t* __restrict__ kf, f16_t* __restrict__ vT,
    const float* Wq, const float* Wk, const float* Wv, const float* Wo,
    const float* Wg, const float* Wu, const float* Wd,
    const float* Ln1, const float* Ln2,
    int lnext, char* __restrict__ imgnext)
{
    __shared__ __align__(128) char smem[49152];
    if (blockIdx.x >= 256) {
        conv_tile(blockIdx.x - 256, lnext, Wq, Wk, Wv, Wo, Wg, Wu, Wd,
                  Ln1, Ln2, imgnext, smem);
        return;
    }
    f32x4 acc[2][4];
    int bm, bn;
    gemm_regA<32>(h, Bimg, smem, blockIdx.x, acc, bm, bn);

    int tid = threadIdx.x;
    int wv = tid >> 6, l = tid & 63, lg = l >> 4, lr = l & 15;
    int wr = wv >> 1, wc = wv & 1;
    float (*X)[132] = (float (*)[132])smem;
    float* sl = (float*)(smem + 64 * 132 * 4 + 128);
    __syncthreads();
#pragma unroll
    for (int i = 0; i < 2; ++i)
#pragma unroll
        for (int j = 0; j < 4; ++j)
#pragma unroll
            for (int ii = 0; ii < 4; ++ii)
                X[wr * 32 + i * 16 + lg * 4 + ii][wc * 64 + j * 16 + lr] = acc[i][j][ii];
    int t0 = bm * 64;
    if (bn >= 24) row_scales(h, t0, sl);
    __syncthreads();

    if (bn < 24) {
        bool isq = bn < 16;
        int slot = isq ? bn : bn - 16;
        const float* wn = isq ? qw : kw;
        int r = tid >> 2, part = tid & 3;
        float ss = 0.f;
#pragma unroll
        for (int c = 0; c < 32; ++c) { float v = X[r][part * 32 + c]; ss += v * v; }
        ss += __shfl_xor(ss, 1);
        ss += __shfl_xor(ss, 2);
        float sc = rsqrtf(ss * (1.0f / 128.0f) + 1e-6f);
        int t = t0 + r;
        int d0 = part * 16;
        float o1v[16], o2v[16];
#pragma unroll
        for (int c = 0; c < 16; ++c) {
            int d = d0 + c;
            float xv1 = X[r][d] * sc * wn[d];
            float xv2 = X[r][d + 64] * sc * wn[d + 64];
            o1v[c] = xv1 * cosb[t * HD + d] - xv2 * sinb[t * HD + d];
            o2v[c] = xv2 * cosb[t * HD + d + 64] + xv1 * sinb[t * HD + d + 64];
        }
        f16x8 w0, w1, w2, w3;
#pragma unroll
        for (int c = 0; c < 8; ++c) {
            w0[c] = (f16_t)o1v[c];     w1[c] = (f16_t)o1v[8 + c];
            w2[c] = (f16_t)o2v[c];     w3[c] = (f16_t)o2v[8 + c];
        }
        f16_t* o = (isq ? qf : kf) + ((size_t)slot * SEQ + t) * HD;
        *(f16x8*)(o + d0) = w0;
        *(f16x8*)(o + d0 + 8) = w1;
        *(f16x8*)(o + d0 + 64) = w2;
        *(f16x8*)(o + d0 + 72) = w3;
    } else {
        int kvh = bn - 24;
#pragma unroll
        for (int it = 0; it < 4; ++it) {
            int task = it * 256 + tid;
            int d = task >> 3, seg = task & 7;
            f16x8 o;
#pragma unroll
            for (int j = 0; j < 8; ++j)
                o[j] = (f16_t)(X[seg * 8 + j][d] * sl[seg * 8 + j]);
            *(f16x8*)(vT + ((size_t)kvh * HD + d) * SEQ + t0 + seg * 8) = o;
        }
    }
}

// ---------------------------------------------------------------------------
// wo GEMM (image A, split-K4) -> f32 atomicAdd into h
__global__ __launch_bounds__(256) void g_wo(
    const char* __restrict__ A, const char* __restrict__ B,
    float* __restrict__ h,
    const float* Wq, const float* Wk, const float* Wv, const float* Wo,
    const float* Wg, const float* Wu, const float* Wd,
    const float* Ln1, const float* Ln2,
    int lnext, char* imgnext)
{
    __shared__ __align__(128) char smem[73728];
    if (blockIdx.x >= 256) {
        conv_tile(blockIdx.x - 256 + 960, lnext, Wq, Wk, Wv, Wo, Wg, Wu, Wd,
                  Ln1, Ln2, imgnext, smem);
        return;
    }
    f32x4 acc[2][4];
    int bm, bn;
    gemm_img<8, 4, 32>(A, B, smem, blockIdx.x, acc, bm, bn);
    int tid = threadIdx.x;
    int wv = tid >> 6, l = tid & 63, lg = l >> 4, lr = l & 15;
    int wr = wv >> 1, wc = wv & 1;
#pragma unroll
    for (int i = 0; i < 2; ++i)
#pragma unroll
        for (int j = 0; j < 4; ++j)
#pragma unroll
            for (int ii = 0; ii < 4; ++ii) {
                int row = bm * 64 + wr * 32 + i * 16 + lg * 4 + ii;
                int col = bn * 128 + wc * 64 + j * 16 + lr;
                atomicAdd(&h[(size_t)row * 1024 + col], acc[i][j][ii]);
            }
}

// ---------------------------------------------------------------------------
// gu GEMM (reg-A from h, ln2-folded paired B) + row scale + swiglu -> mimg
__global__ __launch_bounds__(256) void g_gu(
    const float* __restrict__ h, const char* __restrict__ B,
    char* __restrict__ mimg,
    const float* Wq, const float* Wk, const float* Wv, const float* Wo,
    const float* Wg, const float* Wu, const float* Wd,
    const float* Ln1, const float* Ln2,
    int lnext, char* imgnext)
{
    __shared__ __align__(128) char smem[49152];
    if (blockIdx.x >= 384) {
        conv_tile(blockIdx.x - 384 + 1920, lnext, Wq, Wk, Wv, Wo, Wg, Wu, Wd,
                  Ln1, Ln2, imgnext, smem);
        return;
    }
    f32x4 acc[2][4];
    int bm, bn;
    gemm_regA<48>(h, B, smem, blockIdx.x, acc, bm, bn);
    int tid = threadIdx.x;
    int wv = tid >> 6, l = tid & 63, lg = l >> 4, lr = l & 15;
    int wr = wv >> 1, wc = wv & 1;
    float* sarr = (float*)smem;
    __syncthreads();
    row_scales(h, bm * 64, sarr);
    __syncthreads();
#pragma unroll
    for (int i = 0; i < 2; ++i)
#pragma unroll
        for (int jp = 0; jp < 2; ++jp)
#pragma unroll
            for (int ii = 0; ii < 4; ++ii) {
                int lrow = wr * 32 + i * 16 + lg * 4 + ii;
                int row = bm * 64 + lrow;
                int col = (bn * 2 + wc) * 32 + jp * 16 + lr;
                float s = sarr[lrow];
                float gv = acc[i][2 * jp][ii] * s;
                float uv = acc[i][2 * jp + 1][ii] * s;
                float val = gv / (1.f + __expf(-gv)) * uv;
                *(bf16_t*)(mimg + aoff(row, col, 48)) = (bf16_t)val;
            }
}

// ---------------------------------------------------------------------------
// wd GEMM (image A = mimg, split-K4) -> f32 atomicAdd into target (h or out)
__global__ __launch_bounds__(256) void g_wd(
    const char* __restrict__ A, const char* __restrict__ B,
    float* __restrict__ target,
    const float* Wq, const float* Wk, const float* Wv, const float* Wo,
    const float* Wg, const float* Wu, const float* Wd,
    const float* Ln1, const float* Ln2,
    int lnext, char* imgnext)
{
    __shared__ __align__(128) char smem[73728];
    if (blockIdx.x >= 256) {
        conv_tile(blockIdx.x - 256 + 2880, lnext, Wq, Wk, Wv, Wo, Wg, Wu, Wd,
                  Ln1, Ln2, imgnext, smem);
        return;
    }
    f32x4 acc[2][4];
    int bm, bn;
    gemm_img<8, 4, 48>(A, B, smem, blockIdx.x, acc, bm, bn);
    int tid = threadIdx.x;
    int wv = tid >> 6, l = tid & 63, lg = l >> 4, lr = l & 15;
    int wr = wv >> 1, wc = wv & 1;
#pragma unroll
    for (int i = 0; i < 2; ++i)
#pragma unroll
        for (int j = 0; j < 4; ++j)
#pragma unroll
            for (int ii = 0; ii < 4; ++ii) {
                int row = bm * 64 + wr * 32 + i * 16 + lg * 4 + ii;
                int col = bn * 128 + wc * 64 + j * 16 + lr;
                atomicAdd(&target[(size_t)row * 1024 + col], acc[i][j][ii]);
            }
}

// ---------------------------------------------------------------------------
// causal flash attention -> attn-out image; heavy q-tiles launched first.
__global__ __launch_bounds__(128) void k_attn(
    const f16_t* __restrict__ qf, const f16_t* __restrict__ kf,
    const f16_t* __restrict__ vT, char* __restrict__ attimg)
{
    int h = blockIdx.x >> 4, qb = 15 - (blockIdx.x & 15);
    int kvh = h >> 1;
    __shared__ f16_t Kt[64][136];
    __shared__ f16_t Vt[128][72];
    __shared__ f16_t Pl[2][16][72];
    int tid = threadIdx.x;
    int wv = tid >> 6, l = tid & 63, lg = l >> 4, lr = l & 15;
    int q0 = qb * 32;
    int qrow = q0 + wv * 16;

    f16x8 aq[4];
    const f16_t* qp = qf + ((size_t)h * SEQ + qrow + lr) * HD;
#pragma unroll
    for (int c = 0; c < 4; ++c) aq[c] = *(const f16x8*)(qp + c * 32 + lg * 8);

    f32x4 accv[8];
#pragma unroll
    for (int df = 0; df < 8; ++df) { f32x4 z = {0.f, 0.f, 0.f, 0.f}; accv[df] = z; }
    float mrun[4], lrun[4];
#pragma unroll
    for (int ii = 0; ii < 4; ++ii) { mrun[ii] = -3e38f; lrun[ii] = 0.f; }

    int ktiles = (q0 + 32 + 63) >> 6;
    for (int kt = 0; kt < ktiles; ++kt) {
        int kt0 = kt * 64;
        __syncthreads();
#pragma unroll
        for (int it = 0; it < 8; ++it) {
            int idx = it * 128 + tid;
            int r = idx >> 4, seg = idx & 15;
            *(int4*)&Kt[r][seg * 8] =
                *(const int4*)(kf + ((size_t)kvh * SEQ + kt0 + r) * HD + seg * 8);
        }
#pragma unroll
        for (int it = 0; it < 8; ++it) {
            int idx = it * 128 + tid;
            int r = idx >> 3, seg = idx & 7;
            *(int4*)&Vt[r][seg * 8] =
                *(const int4*)(vT + ((size_t)kvh * HD + r) * SEQ + kt0 + seg * 8);
        }
        __syncthreads();

        f32x4 s[4];
#pragma unroll
        for (int nf = 0; nf < 4; ++nf) {
            f32x4 a = {0.f, 0.f, 0.f, 0.f};
#pragma unroll
            for (int c = 0; c < 4; ++c) {
                f16x8 bk = *(const f16x8*)&Kt[nf * 16 + lr][c * 32 + lg * 8];
                a = __builtin_amdgcn_mfma_f32_16x16x32_f16(aq[c], bk, a, 0, 0, 0);
            }
            s[nf] = a;
        }
        const float scale = 0.08838834764831845f;
        float tmax[4] = {-3e38f, -3e38f, -3e38f, -3e38f};
#pragma unroll
        for (int nf = 0; nf < 4; ++nf) {
            int ktg = kt0 + nf * 16 + lr;
#pragma unroll
            for (int ii = 0; ii < 4; ++ii) {
                int qg = qrow + lg * 4 + ii;
                float vv = s[nf][ii] * scale;
                vv = (ktg <= qg) ? vv : -1e30f;
                s[nf][ii] = vv;
                tmax[ii] = fmaxf(tmax[ii], vv);
            }
        }
#pragma unroll
        for (int m = 1; m < 16; m <<= 1)
#pragma unroll
            for (int ii = 0; ii < 4; ++ii)
                tmax[ii] = fmaxf(tmax[ii], __shfl_xor(tmax[ii], m));
        float corr[4];
#pragma unroll
        for (int ii = 0; ii < 4; ++ii) {
            float mnew = fmaxf(mrun[ii], tmax[ii]);
            corr[ii] = __expf(mrun[ii] - mnew);
            mrun[ii] = mnew;
        }
        float tsum[4] = {0.f, 0.f, 0.f, 0.f};
#pragma unroll
        for (int nf = 0; nf < 4; ++nf)
#pragma unroll
            for (int ii = 0; ii < 4; ++ii) {
                float pp = __expf(s[nf][ii] - mrun[ii]);
                s[nf][ii] = pp;
                tsum[ii] += pp;
            }
#pragma unroll
        for (int m = 1; m < 16; m <<= 1)
#pragma unroll
            for (int ii = 0; ii < 4; ++ii) tsum[ii] += __shfl_xor(tsum[ii], m);
#pragma unroll
        for (int ii = 0; ii < 4; ++ii) lrun[ii] = lrun[ii] * corr[ii] + tsum[ii];
#pragma unroll
        for (int df = 0; df < 8; ++df)
#pragma unroll
            for (int ii = 0; ii < 4; ++ii) accv[df][ii] *= corr[ii];
#pragma unroll
        for (int nf = 0; nf < 4; ++nf)
#pragma unroll
            for (int ii = 0; ii < 4; ++ii)
                Pl[wv][lg * 4 + ii][nf * 16 + lr] = (f16_t)s[nf][ii];
        __syncthreads();
#pragma unroll
        for (int c = 0; c < 2; ++c) {
            f16x8 ap = *(const f16x8*)&Pl[wv][lr][c * 32 + lg * 8];
#pragma unroll
            for (int df = 0; df < 8; ++df) {
                f16x8 bv = *(const f16x8*)&Vt[df * 16 + lr][c * 32 + lg * 8];
                accv[df] = __builtin_amdgcn_mfma_f32_16x16x32_f16(ap, bv, accv[df], 0, 0, 0);
            }
        }
    }
#pragma unroll
    for (int df = 0; df < 8; ++df)
#pragma unroll
        for (int ii = 0; ii < 4; ++ii) {
            int qg = qrow + lg * 4 + ii;
            int col = h * HD + df * 16 + lr;
            *(bf16_t*)(attimg + aoff(qg, col, 32)) =
                (bf16_t)(accv[df][ii] / lrun[ii]);
        }
}

// ---------------------------------------------------------------------------
extern "C" void kernel_launch(void* const* d_in, const int* in_sizes, int n_in,
                              void* d_out, int out_size, void* d_ws, size_t ws_size,
                              hipStream_t stream)
{
    const float* hin  = (const float*)d_in[0];
    const float* cosb = (const float*)d_in[1];
    const float* sinb = (const float*)d_in[2];
    const float* Wq = (const float*)d_in[4];
    const float* Wk = (const float*)d_in[5];
    const float* Wv = (const float*)d_in[6];
    const float* Wo = (const float*)d_in[7];
    const float* Wg = (const float*)d_in[8];
    const float* Wu = (const float*)d_in[9];
    const float* Wd = (const float*)d_in[10];
    const float* Ln1 = (const float*)d_in[11];
    const float* Ln2 = (const float*)d_in[12];
    const float* Qn = (const float*)d_in[13];
    const float* Kn = (const float*)d_in[14];

    char* p = (char*)d_ws;
    auto alloc = [&](size_t bytes) { char* r = p; p += bytes; return r; };
    float*  h     = (float*)alloc(2097152);
    char*   attimg= alloc(2097152);
    char*   mimg  = alloc(3145728);
    f16_t*  qf    = (f16_t*)alloc(2097152);
    f16_t*  kf    = (f16_t*)alloc(1048576);
    f16_t*  vT    = (f16_t*)alloc(1048576);
    char*   imgA  = alloc(IMG_LAYER_BYTES);
    size_t fixed = (size_t)(imgA + IMG_LAYER_BYTES - (char*)d_ws);
    bool pp = ws_size >= fixed + IMG_LAYER_BYTES;
    char* imgB = pp ? alloc(IMG_LAYER_BYTES) : imgA;

    k_copy<<<512, 256, 0, stream>>>(hin, h);
    k_conv<<<3840, 256, 0, stream>>>(0, Wq, Wk, Wv, Wo, Wg, Wu, Wd, Ln1, Ln2, imgA);

    for (int l = 0; l < 28; ++l) {
        char* img  = pp ? ((l & 1) ? imgB : imgA) : imgA;
        char* imgn = pp ? ((l & 1) ? imgA : imgB) : imgA;
        bool cv = pp && (l < 27);
        int ln = l + 1;

        if (!pp && l > 0)
            k_conv<<<3840, 256, 0, stream>>>(l, Wq, Wk, Wv, Wo, Wg, Wu, Wd,
                                             Ln1, Ln2, imgA);

        g_qkv<<<cv ? 1216 : 256, 256, 0, stream>>>(
            h, img + IMG_QKV, cosb, sinb,
            Qn + (size_t)l * 128, Kn + (size_t)l * 128, qf, kf, vT,
            Wq, Wk, Wv, Wo, Wg, Wu, Wd, Ln1, Ln2, ln, imgn);
        k_attn<<<256, 128, 0, stream>>>(qf, kf, vT, attimg);
        g_wo<<<cv ? 1216 : 256, 256, 0, stream>>>(
            attimg, img + IMG_WO, h,
            Wq, Wk, Wv, Wo, Wg, Wu, Wd, Ln1, Ln2, ln, imgn);
        g_gu<<<cv ? 1344 : 384, 256, 0, stream>>>(
            h, img + IMG_GU, mimg,
            Wq, Wk, Wv, Wo, Wg, Wu, Wd, Ln1, Ln2, ln, imgn);
        if (l == 27)
            k_copy<<<512, 256, 0, stream>>>(h, (float*)d_out);
        g_wd<<<cv ? 1216 : 256, 256, 0, stream>>>(
            mimg, img + IMG_WD, (l == 27) ? (float*)d_out : h,
            Wq, Wk, Wv, Wo, Wg, Wu, Wd, Ln1, Ln2, ln, imgn);
    }
}